// Round 1
// baseline (448.861 us; speedup 1.0000x reference)
//
#include <hip/hip_runtime.h>
#include <hip/hip_bf16.h>

typedef unsigned short u16;
using short8 = __attribute__((ext_vector_type(8))) short;
using f32x4  = __attribute__((ext_vector_type(4))) float;
using f32x4v = __attribute__((ext_vector_type(4))) float;
using u16x4  = __attribute__((ext_vector_type(4))) unsigned short;

#define B_  4
#define L_  2048
#define S_  2048
#define DM  1024
#define H_  16
#define E_  64

__device__ __forceinline__ u16 f2bf(float f) {
  union { float f; unsigned u; } v; v.f = f;
  unsigned u = v.u;
  unsigned r = (u + 0x7fffu + ((u >> 16) & 1u)) >> 16;  // RNE
  return (u16)r;
}

__device__ __forceinline__ f32x4 mfma16(short8 a, short8 b, f32x4 c) {
  return __builtin_amdgcn_mfma_f32_16x16x32_bf16(a, b, c, 0, 0, 0);
}

__device__ __forceinline__ void gload_lds16(const u16* g, u16* l) {
  __builtin_amdgcn_global_load_lds(
      (const __attribute__((address_space(1))) unsigned int*)(const void*)g,
      (__attribute__((address_space(3))) unsigned int*)(void*)l, 16, 0, 0);
}

// ---------------- fp32 -> bf16 convert (vectorized) ----------------
__global__ __launch_bounds__(256) void cvt_f32_bf16(const float* __restrict__ in,
                                                    u16* __restrict__ out) {
  int i = (blockIdx.x * 256 + threadIdx.x) * 4;
  f32x4v v = *(const f32x4v*)(in + i);
  u16x4 o;
  o.x = f2bf(v.x); o.y = f2bf(v.y); o.z = f2bf(v.z); o.w = f2bf(v.w);
  *(u16x4*)(out + i) = o;
}

// ---------------- weight transpose + convert: Wt[n][k] = bf16(W[k][n]) ------
__global__ __launch_bounds__(256) void transpose_w(const float* __restrict__ W,
                                                   u16* __restrict__ Wt) {
  __shared__ float t[32][33];
  int tx = threadIdx.x, ty = threadIdx.y;
#pragma unroll
  for (int j = 0; j < 32; j += 8)
    t[ty + j][tx] = W[(size_t)(blockIdx.y * 32 + ty + j) * DM + blockIdx.x * 32 + tx];
  __syncthreads();
#pragma unroll
  for (int j = 0; j < 32; j += 8)
    Wt[(size_t)(blockIdx.x * 32 + ty + j) * DM + blockIdx.y * 32 + tx] = f2bf(t[tx][ty + j]);
}

// ---------------- GEMM: C[M,N] = A[M,K] * Bt[N,K]^T + bias -----------------
// EPI 0: bf16 row-major out, +bias
// EPI 1: bf16 out written transposed per (batch,col): Vt[(b*DM+col)*S_ + s], +bias
// EPI 2: fp32 row-major out, +bias
template <int EPI>
__global__ __launch_bounds__(256) void gemm_bt(const u16* __restrict__ A,
                                               const u16* __restrict__ Bt,
                                               const float* __restrict__ bias,
                                               void* __restrict__ Cout,
                                               int M, int N, int K) {
  __shared__ u16 lA[128 * 32];
  __shared__ u16 lB[128 * 32];
  const int tid = threadIdx.x, wid = tid >> 6, lane = tid & 63;
  const int lr = lane & 15, lh = lane >> 4;
  const int m0 = blockIdx.y * 128, n0 = blockIdx.x * 128;
  const int wr = wid >> 1, wc = wid & 1;

  f32x4 acc[4][4];
#pragma unroll
  for (int m = 0; m < 4; m++)
#pragma unroll
    for (int n = 0; n < 4; n++) acc[m][n] = (f32x4){0.f, 0.f, 0.f, 0.f};

  const int srow = wid * 16 + (lane >> 2);
  const int scol = (lane & 3) * 8;

  for (int k0 = 0; k0 < K; k0 += 32) {
#pragma unroll
    for (int p = 0; p < 2; p++) {
      int r = p * 64 + srow;
      gload_lds16(A + (size_t)(m0 + r) * K + k0 + scol, lA + (p * 64 + wid * 16) * 32);
      gload_lds16(Bt + (size_t)(n0 + r) * K + k0 + scol, lB + (p * 64 + wid * 16) * 32);
    }
    __syncthreads();
    short8 af[4], bf[4];
#pragma unroll
    for (int m = 0; m < 4; m++)
      af[m] = *(const short8*)(lA + (wr * 64 + m * 16 + lr) * 32 + lh * 8);
#pragma unroll
    for (int n = 0; n < 4; n++)
      bf[n] = *(const short8*)(lB + (wc * 64 + n * 16 + lr) * 32 + lh * 8);
#pragma unroll
    for (int m = 0; m < 4; m++)
#pragma unroll
      for (int n = 0; n < 4; n++) acc[m][n] = mfma16(af[m], bf[n], acc[m][n]);
    __syncthreads();
  }

#pragma unroll
  for (int m = 0; m < 4; m++) {
    int grow0 = m0 + wr * 64 + m * 16 + lh * 4;
#pragma unroll
    for (int n = 0; n < 4; n++) {
      int gcol = n0 + wc * 64 + n * 16 + lr;
      float bi = bias[gcol];
#pragma unroll
      for (int r = 0; r < 4; r++) {
        int grow = grow0 + r;
        float v = acc[m][n][r] + bi;
        if constexpr (EPI == 0) {
          ((u16*)Cout)[(size_t)grow * N + gcol] = f2bf(v);
        } else if constexpr (EPI == 1) {
          int bb = grow >> 11, sl = grow & 2047;
          ((u16*)Cout)[((size_t)(bb * DM) + gcol) * S_ + sl] = f2bf(v);
        } else {
          ((float*)Cout)[(size_t)grow * N + gcol] = v;
        }
      }
    }
  }
}

// ---------------- flash attention ----------------
// grid (L/64, H, B), 256 threads (4 waves x 16 q-rows). K tile [s][e], V tile
// pre-transposed in global ([b,h,e][s]) so both MFMA operand reads are
// k-contiguous ds_read_b128. Online softmax, wave-parallel shfl reductions.
__global__ __launch_bounds__(256) void attn(const u16* __restrict__ Q,
                                            const u16* __restrict__ Kp,
                                            const u16* __restrict__ Vt,
                                            u16* __restrict__ O) {
  __shared__ u16 lK[64 * 64];
  __shared__ u16 lV[64 * 64];
  __shared__ u16 lP[4][16 * 64];
  const int tid = threadIdx.x, wid = tid >> 6, lane = tid & 63;
  const int lr = lane & 15, lh = lane >> 4;
  const int b = blockIdx.z, h = blockIdx.y, q0 = blockIdx.x * 64;

  const u16* Qb = Q + ((size_t)(b * L_ + q0 + wid * 16 + lr)) * DM + h * E_;
  short8 aq0 = *(const short8*)(Qb + lh * 8);
  short8 aq1 = *(const short8*)(Qb + 32 + lh * 8);

  f32x4 o[4];
  float m_r[4], l_r[4];
#pragma unroll
  for (int e = 0; e < 4; e++) o[e] = (f32x4){0.f, 0.f, 0.f, 0.f};
#pragma unroll
  for (int r = 0; r < 4; r++) { m_r[r] = -3.0e38f; l_r[r] = 0.f; }

  const u16* Kb = Kp + ((size_t)(b * S_)) * DM + h * E_;
  const u16* Vb = Vt + ((size_t)(b * DM + h * E_)) * S_;
  const int g_r = lane >> 3, g_c = (lane & 7) * 8;

  for (int kb = 0; kb < S_; kb += 64) {
#pragma unroll
    for (int p = 0; p < 2; p++) {
      int row = p * 32 + wid * 8 + g_r;
      gload_lds16(Kb + (size_t)(kb + row) * DM + g_c, lK + (p * 32 + wid * 8) * 64);
      gload_lds16(Vb + (size_t)row * S_ + kb + g_c, lV + (p * 32 + wid * 8) * 64);
    }
    __syncthreads();

    // QK^T: 4 col-tiles of 16, K-dim 64 = 2 mfma each
    f32x4 s[4];
#pragma unroll
    for (int kt = 0; kt < 4; kt++) {
      f32x4 a = (f32x4){0.f, 0.f, 0.f, 0.f};
      const u16* kp0 = lK + (kt * 16 + lr) * 64 + lh * 8;
      a = mfma16(aq0, *(const short8*)kp0, a);
      a = mfma16(aq1, *(const short8*)(kp0 + 32), a);
      s[kt] = a * 0.125f;  // 1/sqrt(64)
    }

    // online softmax (rows = lh*4 + r, cols spread over 16 lanes lr)
    float rmax[4];
#pragma unroll
    for (int r = 0; r < 4; r++)
      rmax[r] = fmaxf(fmaxf(s[0][r], s[1][r]), fmaxf(s[2][r], s[3][r]));
#pragma unroll
    for (int off = 1; off < 16; off <<= 1)
#pragma unroll
      for (int r = 0; r < 4; r++) rmax[r] = fmaxf(rmax[r], __shfl_xor(rmax[r], off));

    float al[4], rs[4];
#pragma unroll
    for (int r = 0; r < 4; r++) {
      float mn = fmaxf(m_r[r], rmax[r]);
      al[r] = __expf(m_r[r] - mn);
      m_r[r] = mn;
      rs[r] = 0.f;
    }

    u16* Pw = lP[wid];
#pragma unroll
    for (int kt = 0; kt < 4; kt++)
#pragma unroll
      for (int r = 0; r < 4; r++) {
        float p = __expf(s[kt][r] - m_r[r]);
        rs[r] += p;
        Pw[(lh * 4 + r) * 64 + kt * 16 + lr] = f2bf(p);
      }
#pragma unroll
    for (int off = 1; off < 16; off <<= 1)
#pragma unroll
      for (int r = 0; r < 4; r++) rs[r] += __shfl_xor(rs[r], off);
#pragma unroll
    for (int r = 0; r < 4; r++) l_r[r] = l_r[r] * al[r] + rs[r];
#pragma unroll
    for (int e = 0; e < 4; e++) {
      f32x4 t = o[e];
#pragma unroll
      for (int r = 0; r < 4; r++) t[r] *= al[r];
      o[e] = t;
    }

    // PV: out[16q,64e] += P[16,64] * V[64,64]
#pragma unroll
    for (int kc = 0; kc < 2; kc++) {
      short8 pa = *(const short8*)(Pw + lr * 64 + kc * 32 + lh * 8);
#pragma unroll
      for (int e = 0; e < 4; e++) {
        short8 vb = *(const short8*)(lV + (e * 16 + lr) * 64 + kc * 32 + lh * 8);
        o[e] = mfma16(pa, vb, o[e]);
      }
    }
    __syncthreads();
  }

  u16* Ob = O + ((size_t)(b * L_ + q0 + wid * 16 + lh * 4)) * DM + h * E_;
#pragma unroll
  for (int e = 0; e < 4; e++)
#pragma unroll
    for (int r = 0; r < 4; r++)
      Ob[(size_t)r * DM + e * 16 + lr] = f2bf(o[e][r] / l_r[r]);
}

extern "C" void kernel_launch(void* const* d_in, const int* in_sizes, int n_in,
                              void* d_out, int out_size, void* d_ws, size_t ws_size,
                              hipStream_t stream) {
  (void)in_sizes; (void)n_in; (void)out_size; (void)ws_size;
  const float* q  = (const float*)d_in[0];
  const float* k  = (const float*)d_in[1];
  const float* v  = (const float*)d_in[2];
  const float* Wq = (const float*)d_in[3];
  const float* bq = (const float*)d_in[4];
  const float* Wk = (const float*)d_in[5];
  const float* bk = (const float*)d_in[6];
  const float* Wv = (const float*)d_in[7];
  const float* bv = (const float*)d_in[8];
  const float* Wo = (const float*)d_in[9];
  const float* bo = (const float*)d_in[10];

  char* w = (char*)d_ws;
  const size_t ACT = (size_t)B_ * L_ * DM * 2;  // 16 MiB
  const size_t WT  = (size_t)DM * DM * 2;       // 2 MiB
  u16* qb  = (u16*)w; w += ACT;
  u16* kb  = (u16*)w; w += ACT;
  u16* vb  = (u16*)w; w += ACT;
  u16* WqT = (u16*)w; w += WT;
  u16* WkT = (u16*)w; w += WT;
  u16* WvT = (u16*)w; w += WT;
  u16* WoT = (u16*)w; w += WT;
  u16* Qp  = (u16*)w; w += ACT;
  u16* Kp  = (u16*)w; w += ACT;
  u16* Vt  = (u16*)w; w += ACT;
  u16* At  = (u16*)w; w += ACT;
  // total ws use: 7*16MiB + 4*2MiB = 120 MiB

  const int M = B_ * L_;  // 8192
  int nblk = M * DM / (4 * 256);  // 8192
  cvt_f32_bf16<<<nblk, 256, 0, stream>>>(q, qb);
  cvt_f32_bf16<<<nblk, 256, 0, stream>>>(k, kb);
  cvt_f32_bf16<<<nblk, 256, 0, stream>>>(v, vb);

  dim3 tb(32, 8), tg(32, 32);
  transpose_w<<<tg, tb, 0, stream>>>(Wq, WqT);
  transpose_w<<<tg, tb, 0, stream>>>(Wk, WkT);
  transpose_w<<<tg, tb, 0, stream>>>(Wv, WvT);
  transpose_w<<<tg, tb, 0, stream>>>(Wo, WoT);

  dim3 gg(DM / 128, M / 128);  // (8, 64)
  gemm_bt<0><<<gg, 256, 0, stream>>>(qb, WqT, bq, Qp, M, DM, DM);
  gemm_bt<0><<<gg, 256, 0, stream>>>(kb, WkT, bk, Kp, M, DM, DM);
  gemm_bt<1><<<gg, 256, 0, stream>>>(vb, WvT, bv, Vt, M, DM, DM);

  attn<<<dim3(L_ / 64, H_, B_), 256, 0, stream>>>(Qp, Kp, Vt, At);

  gemm_bt<2><<<gg, 256, 0, stream>>>(At, WoT, bo, (float*)d_out, M, DM, DM);
}

// Round 2
// 379.456 us; speedup vs baseline: 1.1829x; 1.1829x over previous
//
#include <hip/hip_runtime.h>
#include <hip/hip_bf16.h>

typedef unsigned short u16;
using short8 = __attribute__((ext_vector_type(8))) short;
using f32x4  = __attribute__((ext_vector_type(4))) float;
using f32x4v = __attribute__((ext_vector_type(4))) float;
using u16x4  = __attribute__((ext_vector_type(4))) unsigned short;

#define B_  4
#define L_  2048
#define S_  2048
#define DM  1024
#define H_  16
#define E_  64

__device__ __forceinline__ u16 f2bf(float f) {
  union { float f; unsigned u; } v; v.f = f;
  unsigned u = v.u;
  unsigned r = (u + 0x7fffu + ((u >> 16) & 1u)) >> 16;  // RNE
  return (u16)r;
}

__device__ __forceinline__ f32x4 mfma16(short8 a, short8 b, f32x4 c) {
  return __builtin_amdgcn_mfma_f32_16x16x32_bf16(a, b, c, 0, 0, 0);
}

__device__ __forceinline__ void gload_lds16(const u16* g, u16* l) {
  __builtin_amdgcn_global_load_lds(
      (const __attribute__((address_space(1))) unsigned int*)(const void*)g,
      (__attribute__((address_space(3))) unsigned int*)(void*)l, 16, 0, 0);
}

// ---------------- fp32 -> bf16 convert (vectorized) ----------------
__global__ __launch_bounds__(256) void cvt_f32_bf16(const float* __restrict__ in,
                                                    u16* __restrict__ out) {
  int i = (blockIdx.x * 256 + threadIdx.x) * 4;
  f32x4v v = *(const f32x4v*)(in + i);
  u16x4 o;
  o.x = f2bf(v.x); o.y = f2bf(v.y); o.z = f2bf(v.z); o.w = f2bf(v.w);
  *(u16x4*)(out + i) = o;
}

// ---------------- weight transpose + convert: Wt[n][k] = bf16(W[k][n]) ------
__global__ __launch_bounds__(256) void transpose_w(const float* __restrict__ W,
                                                   u16* __restrict__ Wt) {
  __shared__ float t[32][33];
  int tx = threadIdx.x, ty = threadIdx.y;
#pragma unroll
  for (int j = 0; j < 32; j += 8)
    t[ty + j][tx] = W[(size_t)(blockIdx.y * 32 + ty + j) * DM + blockIdx.x * 32 + tx];
  __syncthreads();
#pragma unroll
  for (int j = 0; j < 32; j += 8)
    Wt[(size_t)(blockIdx.x * 32 + ty + j) * DM + blockIdx.y * 32 + tx] = f2bf(t[tx][ty + j]);
}

// ---------------- GEMM: C[M,N] = A[M,K] * Bt[N,K]^T + bias -----------------
template <int EPI>
__global__ __launch_bounds__(256) void gemm_bt(const u16* __restrict__ A,
                                               const u16* __restrict__ Bt,
                                               const float* __restrict__ bias,
                                               void* __restrict__ Cout,
                                               int M, int N, int K) {
  __shared__ u16 lA[128 * 32];
  __shared__ u16 lB[128 * 32];
  const int tid = threadIdx.x, wid = tid >> 6, lane = tid & 63;
  const int lr = lane & 15, lh = lane >> 4;
  const int m0 = blockIdx.y * 128, n0 = blockIdx.x * 128;
  const int wr = wid >> 1, wc = wid & 1;

  f32x4 acc[4][4];
#pragma unroll
  for (int m = 0; m < 4; m++)
#pragma unroll
    for (int n = 0; n < 4; n++) acc[m][n] = (f32x4){0.f, 0.f, 0.f, 0.f};

  const int srow = wid * 16 + (lane >> 2);
  const int scol = (lane & 3) * 8;

  for (int k0 = 0; k0 < K; k0 += 32) {
#pragma unroll
    for (int p = 0; p < 2; p++) {
      int r = p * 64 + srow;
      gload_lds16(A + (size_t)(m0 + r) * K + k0 + scol, lA + (p * 64 + wid * 16) * 32);
      gload_lds16(Bt + (size_t)(n0 + r) * K + k0 + scol, lB + (p * 64 + wid * 16) * 32);
    }
    __syncthreads();
    short8 af[4], bf[4];
#pragma unroll
    for (int m = 0; m < 4; m++)
      af[m] = *(const short8*)(lA + (wr * 64 + m * 16 + lr) * 32 + lh * 8);
#pragma unroll
    for (int n = 0; n < 4; n++)
      bf[n] = *(const short8*)(lB + (wc * 64 + n * 16 + lr) * 32 + lh * 8);
#pragma unroll
    for (int m = 0; m < 4; m++)
#pragma unroll
      for (int n = 0; n < 4; n++) acc[m][n] = mfma16(af[m], bf[n], acc[m][n]);
    __syncthreads();
  }

#pragma unroll
  for (int m = 0; m < 4; m++) {
    int grow0 = m0 + wr * 64 + m * 16 + lh * 4;
#pragma unroll
    for (int n = 0; n < 4; n++) {
      int gcol = n0 + wc * 64 + n * 16 + lr;
      float bi = bias[gcol];
#pragma unroll
      for (int r = 0; r < 4; r++) {
        int grow = grow0 + r;
        float v = acc[m][n][r] + bi;
        if constexpr (EPI == 0) {
          ((u16*)Cout)[(size_t)grow * N + gcol] = f2bf(v);
        } else if constexpr (EPI == 1) {
          int bb = grow >> 11, sl = grow & 2047;
          ((u16*)Cout)[((size_t)(bb * DM) + gcol) * S_ + sl] = f2bf(v);
        } else {
          ((float*)Cout)[(size_t)grow * N + gcol] = v;
        }
      }
    }
  }
}

// ---------------- flash attention ----------------
// grid (L/64, H, B) remapped XCD-aware. 256 threads = 4 waves x 16 q-rows.
// K tile [s][e], V tile pre-transposed ([b,h,e][s]). All LDS tiles
// XOR-swizzled (byte ^ ((row&7)<<4)) to kill the 16-way row-stride-128B bank
// conflicts; K/V swizzle applied via pre-swizzled global source since
// global_load_lds writes linearly (rule: both-sides-or-neither).
// Double-buffered K/V staging: one barrier per tile, prefetch next tile
// right after the barrier (1-deep pipeline, drained by next barrier's vmcnt).
__global__ __launch_bounds__(256) void attn(const u16* __restrict__ Q,
                                            const u16* __restrict__ Kp,
                                            const u16* __restrict__ Vt,
                                            u16* __restrict__ O) {
  __shared__ u16 lK[2][64 * 64];
  __shared__ u16 lV[2][64 * 64];
  __shared__ u16 lP[4][16 * 64];
  const int tid = threadIdx.x, wid = tid >> 6, lane = tid & 63;
  const int lr = lane & 15, lh = lane >> 4;

  // XCD-aware remap: 2048 blocks, 8 XCDs, contiguous 256-block chunks per XCD
  int lin = blockIdx.x + gridDim.x * (blockIdx.y + gridDim.y * blockIdx.z);
  int swz = (lin & 7) * 256 + (lin >> 3);
  const int b = swz >> 9, h = (swz >> 5) & 15, q0 = (swz & 31) * 64;

  const u16* Qb = Q + ((size_t)(b * L_ + q0 + wid * 16 + lr)) * DM + h * E_;
  short8 aq0 = *(const short8*)(Qb + lh * 8);
  short8 aq1 = *(const short8*)(Qb + 32 + lh * 8);

  f32x4 o[4];
  float m_r[4], l_r[4];
#pragma unroll
  for (int e = 0; e < 4; e++) o[e] = (f32x4){0.f, 0.f, 0.f, 0.f};
#pragma unroll
  for (int r = 0; r < 4; r++) { m_r[r] = -3.0e38f; l_r[r] = 0.f; }

  const u16* Kb = Kp + ((size_t)(b * S_)) * DM + h * E_;
  const u16* Vb = Vt + ((size_t)(b * DM + h * E_)) * S_;
  const int g_r = lane >> 3;                      // row within 8-row group
  const int g_c = ((lane & 7) ^ g_r) * 8;        // pre-swizzled source chunk
  const int sxr = (lr & 7) * 8;                  // read-side XOR (u16 units)

  auto stage = [&](int buf, int kb) {
#pragma unroll
    for (int p = 0; p < 2; p++) {
      int row = p * 32 + wid * 8 + g_r;
      gload_lds16(Kb + (size_t)(kb + row) * DM + g_c, lK[buf] + (p * 32 + wid * 8) * 64);
      gload_lds16(Vb + (size_t)row * S_ + kb + g_c, lV[buf] + (p * 32 + wid * 8) * 64);
    }
  };

  stage(0, 0);
  const int NT = S_ / 64;
  for (int it = 0; it < NT; ++it) {
    const int buf = it & 1;
    __syncthreads();                 // staging of buf complete; prev reads done
    if (it + 1 < NT) stage(buf ^ 1, (it + 1) * 64);

    // QK^T: 4 col-tiles of 16, K-dim 64 = 2 mfma each
    f32x4 s[4];
#pragma unroll
    for (int kt = 0; kt < 4; kt++) {
      f32x4 a = (f32x4){0.f, 0.f, 0.f, 0.f};
      const u16* kp0 = lK[buf] + (kt * 16 + lr) * 64;
      a = mfma16(aq0, *(const short8*)(kp0 + ((lh * 8) ^ sxr)), a);
      a = mfma16(aq1, *(const short8*)(kp0 + ((lh * 8 + 32) ^ sxr)), a);
      s[kt] = a * 0.125f;  // 1/sqrt(64)
    }

    // online softmax (rows = lh*4 + r, cols spread over 16 lanes lr)
    float rmax[4];
#pragma unroll
    for (int r = 0; r < 4; r++)
      rmax[r] = fmaxf(fmaxf(s[0][r], s[1][r]), fmaxf(s[2][r], s[3][r]));
#pragma unroll
    for (int off = 1; off < 16; off <<= 1)
#pragma unroll
      for (int r = 0; r < 4; r++) rmax[r] = fmaxf(rmax[r], __shfl_xor(rmax[r], off));

    float al[4], rs[4];
#pragma unroll
    for (int r = 0; r < 4; r++) {
      float mn = fmaxf(m_r[r], rmax[r]);
      al[r] = __expf(m_r[r] - mn);
      m_r[r] = mn;
      rs[r] = 0.f;
    }

    u16* Pw = lP[wid];
#pragma unroll
    for (int kt = 0; kt < 4; kt++)
#pragma unroll
      for (int r = 0; r < 4; r++) {
        float p = __expf(s[kt][r] - m_r[r]);
        rs[r] += p;
        int row = lh * 4 + r;
        Pw[row * 64 + ((kt * 16 + lr) ^ ((row & 7) * 8))] = f2bf(p);
      }
#pragma unroll
    for (int off = 1; off < 16; off <<= 1)
#pragma unroll
      for (int r = 0; r < 4; r++) rs[r] += __shfl_xor(rs[r], off);
#pragma unroll
    for (int r = 0; r < 4; r++) l_r[r] = l_r[r] * al[r] + rs[r];
#pragma unroll
    for (int e = 0; e < 4; e++) {
      f32x4 t = o[e];
#pragma unroll
      for (int r = 0; r < 4; r++) t[r] *= al[r];
      o[e] = t;
    }

    // PV: out[16q,64e] += P[16,64] * V[64,64]
#pragma unroll
    for (int kc = 0; kc < 2; kc++) {
      short8 pa = *(const short8*)(Pw + lr * 64 + ((kc * 32 + lh * 8) ^ sxr));
#pragma unroll
      for (int e = 0; e < 4; e++) {
        short8 vb = *(const short8*)(lV[buf] + (e * 16 + lr) * 64 + ((kc * 32 + lh * 8) ^ sxr));
        o[e] = mfma16(pa, vb, o[e]);
      }
    }
  }

  u16* Ob = O + ((size_t)(b * L_ + q0 + wid * 16 + lh * 4)) * DM + h * E_;
#pragma unroll
  for (int e = 0; e < 4; e++)
#pragma unroll
    for (int r = 0; r < 4; r++)
      Ob[(size_t)r * DM + e * 16 + lr] = f2bf(o[e][r] / l_r[r]);
}

extern "C" void kernel_launch(void* const* d_in, const int* in_sizes, int n_in,
                              void* d_out, int out_size, void* d_ws, size_t ws_size,
                              hipStream_t stream) {
  (void)in_sizes; (void)n_in; (void)out_size; (void)ws_size;
  const float* q  = (const float*)d_in[0];
  const float* k  = (const float*)d_in[1];
  const float* v  = (const float*)d_in[2];
  const float* Wq = (const float*)d_in[3];
  const float* bq = (const float*)d_in[4];
  const float* Wk = (const float*)d_in[5];
  const float* bk = (const float*)d_in[6];
  const float* Wv = (const float*)d_in[7];
  const float* bv = (const float*)d_in[8];
  const float* Wo = (const float*)d_in[9];
  const float* bo = (const float*)d_in[10];

  char* w = (char*)d_ws;
  const size_t ACT = (size_t)B_ * L_ * DM * 2;  // 16 MiB
  const size_t WT  = (size_t)DM * DM * 2;       // 2 MiB
  u16* qb  = (u16*)w; w += ACT;
  u16* kb  = (u16*)w; w += ACT;
  u16* vb  = (u16*)w; w += ACT;
  u16* WqT = (u16*)w; w += WT;
  u16* WkT = (u16*)w; w += WT;
  u16* WvT = (u16*)w; w += WT;
  u16* WoT = (u16*)w; w += WT;
  u16* Qp  = (u16*)w; w += ACT;
  u16* Kp  = (u16*)w; w += ACT;
  u16* Vt  = (u16*)w; w += ACT;
  u16* At  = (u16*)w; w += ACT;

  const int M = B_ * L_;  // 8192
  int nblk = M * DM / (4 * 256);  // 8192
  cvt_f32_bf16<<<nblk, 256, 0, stream>>>(q, qb);
  cvt_f32_bf16<<<nblk, 256, 0, stream>>>(k, kb);
  cvt_f32_bf16<<<nblk, 256, 0, stream>>>(v, vb);

  dim3 tb(32, 8), tg(32, 32);
  transpose_w<<<tg, tb, 0, stream>>>(Wq, WqT);
  transpose_w<<<tg, tb, 0, stream>>>(Wk, WkT);
  transpose_w<<<tg, tb, 0, stream>>>(Wv, WvT);
  transpose_w<<<tg, tb, 0, stream>>>(Wo, WoT);

  dim3 gg(DM / 128, M / 128);  // (8, 64)
  gemm_bt<0><<<gg, 256, 0, stream>>>(qb, WqT, bq, Qp, M, DM, DM);
  gemm_bt<0><<<gg, 256, 0, stream>>>(kb, WkT, bk, Kp, M, DM, DM);
  gemm_bt<1><<<gg, 256, 0, stream>>>(vb, WvT, bv, Vt, M, DM, DM);

  attn<<<dim3(L_ / 64, H_, B_), 256, 0, stream>>>(Qp, Kp, Vt, At);

  gemm_bt<2><<<gg, 256, 0, stream>>>(At, WoT, bo, (float*)d_out, M, DM, DM);
}

// Round 3
// 292.392 us; speedup vs baseline: 1.5351x; 1.2978x over previous
//
#include <hip/hip_runtime.h>
#include <hip/hip_bf16.h>

typedef unsigned short u16;
using short8 = __attribute__((ext_vector_type(8))) short;
using f32x4  = __attribute__((ext_vector_type(4))) float;
using f32x4v = __attribute__((ext_vector_type(4))) float;
using u16x4  = __attribute__((ext_vector_type(4))) unsigned short;

#define B_  4
#define L_  2048
#define S_  2048
#define DM  1024
#define H_  16
#define E_  64

__device__ __forceinline__ u16 f2bf(float f) {
  union { float f; unsigned u; } v; v.f = f;
  unsigned u = v.u;
  unsigned r = (u + 0x7fffu + ((u >> 16) & 1u)) >> 16;  // RNE
  return (u16)r;
}

__device__ __forceinline__ float exp2a(float x) {
  float r; asm("v_exp_f32 %0, %1" : "=v"(r) : "v"(x)); return r;
}

__device__ __forceinline__ unsigned cvtpk(float lo, float hi) {
  unsigned r; asm("v_cvt_pk_bf16_f32 %0, %1, %2" : "=v"(r) : "v"(lo), "v"(hi));
  return r;
}

__device__ __forceinline__ f32x4 mfma16(short8 a, short8 b, f32x4 c) {
  return __builtin_amdgcn_mfma_f32_16x16x32_bf16(a, b, c, 0, 0, 0);
}

__device__ __forceinline__ void gload_lds16(const u16* g, u16* l) {
  __builtin_amdgcn_global_load_lds(
      (const __attribute__((address_space(1))) unsigned int*)(const void*)g,
      (__attribute__((address_space(3))) unsigned int*)(void*)l, 16, 0, 0);
}

// ---------------- fp32 -> bf16 convert (vectorized) ----------------
__global__ __launch_bounds__(256) void cvt_f32_bf16(const float* __restrict__ in,
                                                    u16* __restrict__ out) {
  int i = (blockIdx.x * 256 + threadIdx.x) * 4;
  f32x4v v = *(const f32x4v*)(in + i);
  u16x4 o;
  o.x = f2bf(v.x); o.y = f2bf(v.y); o.z = f2bf(v.z); o.w = f2bf(v.w);
  *(u16x4*)(out + i) = o;
}

// ---------------- weight transpose + convert: Wt[n][k] = bf16(W[k][n]) ------
__global__ __launch_bounds__(256) void transpose_w(const float* __restrict__ W,
                                                   u16* __restrict__ Wt) {
  __shared__ float t[32][33];
  int tx = threadIdx.x, ty = threadIdx.y;
#pragma unroll
  for (int j = 0; j < 32; j += 8)
    t[ty + j][tx] = W[(size_t)(blockIdx.y * 32 + ty + j) * DM + blockIdx.x * 32 + tx];
  __syncthreads();
#pragma unroll
  for (int j = 0; j < 32; j += 8)
    Wt[(size_t)(blockIdx.x * 32 + ty + j) * DM + blockIdx.y * 32 + tx] = f2bf(t[tx][ty + j]);
}

// ---------------- GEMM: C[M,N] = (A[M,K] * Bt[N,K]^T + bias) * oscale ------
template <int EPI>
__global__ __launch_bounds__(256) void gemm_bt(const u16* __restrict__ A,
                                               const u16* __restrict__ Bt,
                                               const float* __restrict__ bias,
                                               void* __restrict__ Cout,
                                               int M, int N, int K, float oscale) {
  __shared__ u16 lA[128 * 32];
  __shared__ u16 lB[128 * 32];
  const int tid = threadIdx.x, wid = tid >> 6, lane = tid & 63;
  const int lr = lane & 15, lh = lane >> 4;
  const int m0 = blockIdx.y * 128, n0 = blockIdx.x * 128;
  const int wr = wid >> 1, wc = wid & 1;

  f32x4 acc[4][4];
#pragma unroll
  for (int m = 0; m < 4; m++)
#pragma unroll
    for (int n = 0; n < 4; n++) acc[m][n] = (f32x4){0.f, 0.f, 0.f, 0.f};

  const int srow = wid * 16 + (lane >> 2);
  const int scol = (lane & 3) * 8;

  for (int k0 = 0; k0 < K; k0 += 32) {
#pragma unroll
    for (int p = 0; p < 2; p++) {
      int r = p * 64 + srow;
      gload_lds16(A + (size_t)(m0 + r) * K + k0 + scol, lA + (p * 64 + wid * 16) * 32);
      gload_lds16(Bt + (size_t)(n0 + r) * K + k0 + scol, lB + (p * 64 + wid * 16) * 32);
    }
    __syncthreads();
    short8 af[4], bf[4];
#pragma unroll
    for (int m = 0; m < 4; m++)
      af[m] = *(const short8*)(lA + (wr * 64 + m * 16 + lr) * 32 + lh * 8);
#pragma unroll
    for (int n = 0; n < 4; n++)
      bf[n] = *(const short8*)(lB + (wc * 64 + n * 16 + lr) * 32 + lh * 8);
#pragma unroll
    for (int m = 0; m < 4; m++)
#pragma unroll
      for (int n = 0; n < 4; n++) acc[m][n] = mfma16(af[m], bf[n], acc[m][n]);
    __syncthreads();
  }

#pragma unroll
  for (int m = 0; m < 4; m++) {
    int grow0 = m0 + wr * 64 + m * 16 + lh * 4;
#pragma unroll
    for (int n = 0; n < 4; n++) {
      int gcol = n0 + wc * 64 + n * 16 + lr;
      float bi = bias[gcol];
#pragma unroll
      for (int r = 0; r < 4; r++) {
        int grow = grow0 + r;
        float v = (acc[m][n][r] + bi) * oscale;
        if constexpr (EPI == 0) {
          ((u16*)Cout)[(size_t)grow * N + gcol] = f2bf(v);
        } else if constexpr (EPI == 1) {
          int bb = grow >> 11, sl = grow & 2047;
          ((u16*)Cout)[((size_t)(bb * DM) + gcol) * S_ + sl] = f2bf(v);
        } else {
          ((float*)Cout)[(size_t)grow * N + gcol] = v;
        }
      }
    }
  }
}

// ---------------- flash attention ----------------
// grid (L/64, H, B) remapped XCD-aware. 256 threads = 4 waves x 16 q-rows.
// Swapped QK^T: s = mfma(K, Q) so each lane holds the 16 scores of ONE q-row
// (q=lr, k=kt*16+lh*4+r) -> row softmax = 15 in-lane fmax + 2 shfl_xor.
// Q comes pre-scaled by 0.125*log2(e) (folded into Q-projection GEMM), so
// p = exp2(s - m) via raw v_exp_f32. P->bf16 via v_cvt_pk_bf16_f32, paired
// ds_write_b32 into per-wave swizzled LDS. Defer-max (THR=8 in log2 domain)
// skips the o-rescale on almost all tiles; exact since m cancels in o/l.
__global__ __launch_bounds__(256) void attn(const u16* __restrict__ Q,
                                            const u16* __restrict__ Kp,
                                            const u16* __restrict__ Vt,
                                            u16* __restrict__ O) {
  __shared__ u16 lK[2][64 * 64];
  __shared__ u16 lV[2][64 * 64];
  __shared__ u16 lP[4][16 * 64];
  const int tid = threadIdx.x, wid = tid >> 6, lane = tid & 63;
  const int lr = lane & 15, lh = lane >> 4;

  int lin = blockIdx.x + gridDim.x * (blockIdx.y + gridDim.y * blockIdx.z);
  int swz = (lin & 7) * 256 + (lin >> 3);
  const int b = swz >> 9, h = (swz >> 5) & 15, q0 = (swz & 31) * 64;

  // Q fragment (B-operand of swapped QK^T): lane lr reads q-row lr
  const u16* Qb = Q + ((size_t)(b * L_ + q0 + wid * 16 + lr)) * DM + h * E_;
  short8 bq0 = *(const short8*)(Qb + lh * 8);
  short8 bq1 = *(const short8*)(Qb + 32 + lh * 8);

  f32x4 o[4];
#pragma unroll
  for (int e = 0; e < 4; e++) o[e] = (f32x4){0.f, 0.f, 0.f, 0.f};
  float m_r = -3.0e38f, l_r = 0.f;

  const u16* Kb = Kp + ((size_t)(b * S_)) * DM + h * E_;
  const u16* Vb = Vt + ((size_t)(b * DM + h * E_)) * S_;
  const int g_r = lane >> 3;                 // row within 8-row group
  const int g_c = ((lane & 7) ^ g_r) * 8;    // pre-swizzled source chunk
  const int sxr = (lr & 7) * 8;              // read-side XOR (u16 units)

  auto stage = [&](int buf, int kb) {
#pragma unroll
    for (int p = 0; p < 2; p++) {
      int row = p * 32 + wid * 8 + g_r;
      gload_lds16(Kb + (size_t)(kb + row) * DM + g_c, lK[buf] + (p * 32 + wid * 8) * 64);
      gload_lds16(Vb + (size_t)row * S_ + kb + g_c, lV[buf] + (p * 32 + wid * 8) * 64);
    }
  };

  stage(0, 0);
  const int NT = S_ / 64;
  for (int it = 0; it < NT; ++it) {
    const int buf = it & 1;
    __syncthreads();
    if (it + 1 < NT) stage(buf ^ 1, (it + 1) * 64);

    // swapped QK^T: A = K-tile rows, B = Q rows. Lane (lr,lh) reg r ->
    // score for q=lr, k=kt*16+lh*4+r (pre-scaled log2 domain).
    f32x4 s[4];
#pragma unroll
    for (int kt = 0; kt < 4; kt++) {
      f32x4 a = (f32x4){0.f, 0.f, 0.f, 0.f};
      const u16* kp0 = lK[buf] + (kt * 16 + lr) * 64;
      a = mfma16(*(const short8*)(kp0 + ((lh * 8) ^ sxr)), bq0, a);
      a = mfma16(*(const short8*)(kp0 + ((lh * 8 + 32) ^ sxr)), bq1, a);
      s[kt] = a;
    }

    // tile max for q=lr: 15 in-lane fmax + cross-lh (2 shfl)
    float t = s[0][0];
#pragma unroll
    for (int kt = 0; kt < 4; kt++)
#pragma unroll
      for (int r = 0; r < 4; r++) t = fmaxf(t, s[kt][r]);
    t = fmaxf(t, __shfl_xor(t, 16));
    t = fmaxf(t, __shfl_xor(t, 32));

    // defer-max: rescale only when tile max exceeds running max by >8 (log2)
    if (__any(t > m_r + 8.f)) {
      float mn = fmaxf(m_r, t);
      float al = exp2a(m_r - mn);
      m_r = mn;
      l_r *= al;
      float alq[4];
#pragma unroll
      for (int r = 0; r < 4; r++) alq[r] = __shfl(al, (lane & 48) | (lh * 4 + r));
#pragma unroll
      for (int e = 0; e < 4; e++)
#pragma unroll
        for (int r = 0; r < 4; r++) o[e][r] *= alq[r];
    }

    // p = exp2(s - m); pack pairs to bf16, store to per-wave P (swizzled)
    u16* Pw = lP[wid];
    float rs = 0.f;
#pragma unroll
    for (int kt = 0; kt < 4; kt++)
#pragma unroll
      for (int j = 0; j < 2; j++) {
        float p0 = exp2a(s[kt][2 * j] - m_r);
        float p1 = exp2a(s[kt][2 * j + 1] - m_r);
        rs += p0 + p1;
        unsigned pk = cvtpk(p0, p1);
        *(unsigned*)(Pw + lr * 64 + ((kt * 16 + lh * 4 + 2 * j) ^ sxr)) = pk;
      }
    rs += __shfl_xor(rs, 16);
    rs += __shfl_xor(rs, 32);
    l_r += rs;

    // PV: out[16q,64e] += P[16,64] * V[64,64]
#pragma unroll
    for (int kc = 0; kc < 2; kc++) {
      short8 pa = *(const short8*)(Pw + lr * 64 + ((kc * 32 + lh * 8) ^ sxr));
#pragma unroll
      for (int e = 0; e < 4; e++) {
        short8 vb = *(const short8*)(lV[buf] + (e * 16 + lr) * 64 + ((kc * 32 + lh * 8) ^ sxr));
        o[e] = mfma16(pa, vb, o[e]);
      }
    }
  }

  // final 1/l per o-row q=lh*4+r (l lives at lane with lr=q)
  float lq[4];
#pragma unroll
  for (int r = 0; r < 4; r++)
    lq[r] = 1.f / __shfl(l_r, (lane & 48) | (lh * 4 + r));

  u16* Ob = O + ((size_t)(b * L_ + q0 + wid * 16 + lh * 4)) * DM + h * E_;
#pragma unroll
  for (int e = 0; e < 4; e++)
#pragma unroll
    for (int r = 0; r < 4; r++)
      Ob[(size_t)r * DM + e * 16 + lr] = f2bf(o[e][r] * lq[r]);
}

extern "C" void kernel_launch(void* const* d_in, const int* in_sizes, int n_in,
                              void* d_out, int out_size, void* d_ws, size_t ws_size,
                              hipStream_t stream) {
  (void)in_sizes; (void)n_in; (void)out_size; (void)ws_size;
  const float* q  = (const float*)d_in[0];
  const float* k  = (const float*)d_in[1];
  const float* v  = (const float*)d_in[2];
  const float* Wq = (const float*)d_in[3];
  const float* bq = (const float*)d_in[4];
  const float* Wk = (const float*)d_in[5];
  const float* bk = (const float*)d_in[6];
  const float* Wv = (const float*)d_in[7];
  const float* bv = (const float*)d_in[8];
  const float* Wo = (const float*)d_in[9];
  const float* bo = (const float*)d_in[10];

  char* w = (char*)d_ws;
  const size_t ACT = (size_t)B_ * L_ * DM * 2;  // 16 MiB
  const size_t WT  = (size_t)DM * DM * 2;       // 2 MiB
  u16* qb  = (u16*)w; w += ACT;
  u16* kb  = (u16*)w; w += ACT;
  u16* vb  = (u16*)w; w += ACT;
  u16* WqT = (u16*)w; w += WT;
  u16* WkT = (u16*)w; w += WT;
  u16* WvT = (u16*)w; w += WT;
  u16* WoT = (u16*)w; w += WT;
  u16* Qp  = (u16*)w; w += ACT;
  u16* Kp  = (u16*)w; w += ACT;
  u16* Vt  = (u16*)w; w += ACT;
  u16* At  = (u16*)w; w += ACT;

  const int M = B_ * L_;  // 8192
  int nblk = M * DM / (4 * 256);  // 8192
  cvt_f32_bf16<<<nblk, 256, 0, stream>>>(q, qb);
  cvt_f32_bf16<<<nblk, 256, 0, stream>>>(k, kb);
  cvt_f32_bf16<<<nblk, 256, 0, stream>>>(v, vb);

  dim3 tb(32, 8), tg(32, 32);
  transpose_w<<<tg, tb, 0, stream>>>(Wq, WqT);
  transpose_w<<<tg, tb, 0, stream>>>(Wk, WkT);
  transpose_w<<<tg, tb, 0, stream>>>(Wv, WvT);
  transpose_w<<<tg, tb, 0, stream>>>(Wo, WoT);

  const float QSC = 0.125f * 1.44269504089f;  // 1/sqrt(64) * log2(e)
  dim3 gg(DM / 128, M / 128);  // (8, 64)
  gemm_bt<0><<<gg, 256, 0, stream>>>(qb, WqT, bq, Qp, M, DM, DM, QSC);
  gemm_bt<0><<<gg, 256, 0, stream>>>(kb, WkT, bk, Kp, M, DM, DM, 1.0f);
  gemm_bt<1><<<gg, 256, 0, stream>>>(vb, WvT, bv, Vt, M, DM, DM, 1.0f);

  attn<<<dim3(L_ / 64, H_, B_), 256, 0, stream>>>(Qp, Kp, Vt, At);

  gemm_bt<2><<<gg, 256, 0, stream>>>(At, WoT, bo, (float*)d_out, M, DM, DM, 1.0f);
}

// Round 4
// 263.957 us; speedup vs baseline: 1.7005x; 1.1077x over previous
//
#include <hip/hip_runtime.h>
#include <hip/hip_bf16.h>

typedef unsigned short u16;
typedef unsigned int u32;
using short8 = __attribute__((ext_vector_type(8))) short;
using f32x4  = __attribute__((ext_vector_type(4))) float;
using u32x2  = __attribute__((ext_vector_type(2))) unsigned int;

#define B_  4
#define L_  2048
#define S_  2048
#define DM  1024
#define H_  16
#define E_  64

__device__ __forceinline__ u16 f2bf(float f) {
  union { float f; unsigned u; } v; v.f = f;
  unsigned u = v.u;
  unsigned r = (u + 0x7fffu + ((u >> 16) & 1u)) >> 16;  // RNE
  return (u16)r;
}

__device__ __forceinline__ float exp2a(float x) {
  float r; asm("v_exp_f32 %0, %1" : "=v"(r) : "v"(x)); return r;
}

__device__ __forceinline__ u32 cvtpk(float lo, float hi) {
  u32 r; asm("v_cvt_pk_bf16_f32 %0, %1, %2" : "=v"(r) : "v"(lo), "v"(hi));
  return r;
}

__device__ __forceinline__ f32x4 mfma16(short8 a, short8 b, f32x4 c) {
  return __builtin_amdgcn_mfma_f32_16x16x32_bf16(a, b, c, 0, 0, 0);
}

__device__ __forceinline__ void gload_lds16(const u16* g, u16* l) {
  __builtin_amdgcn_global_load_lds(
      (const __attribute__((address_space(1))) unsigned int*)(const void*)g,
      (__attribute__((address_space(3))) unsigned int*)(void*)l, 16, 0, 0);
}

// ---------------- fused fp32 -> bf16 convert for q,k,v (one launch) --------
__global__ __launch_bounds__(256) void cvt_all(const float* __restrict__ s0,
                                               const float* __restrict__ s1,
                                               const float* __restrict__ s2,
                                               u16* __restrict__ d0,
                                               u16* __restrict__ d1,
                                               u16* __restrict__ d2) {
  const float* s = blockIdx.y == 0 ? s0 : blockIdx.y == 1 ? s1 : s2;
  u16* d = blockIdx.y == 0 ? d0 : blockIdx.y == 1 ? d1 : d2;
  int i = (blockIdx.x * 256 + threadIdx.x) * 4;
  f32x4 v = *(const f32x4*)(s + i);
  u32x2 o;
  o.x = cvtpk(v.x, v.y);
  o.y = cvtpk(v.z, v.w);
  *(u32x2*)(d + i) = o;
}

// ---------------- fused weight transpose+convert (one launch, z=4) ---------
__global__ __launch_bounds__(256) void transp_all(const float* __restrict__ w0,
                                                  const float* __restrict__ w1,
                                                  const float* __restrict__ w2,
                                                  const float* __restrict__ w3,
                                                  u16* __restrict__ t0,
                                                  u16* __restrict__ t1,
                                                  u16* __restrict__ t2,
                                                  u16* __restrict__ t3) {
  const float* W = blockIdx.z == 0 ? w0 : blockIdx.z == 1 ? w1 :
                   blockIdx.z == 2 ? w2 : w3;
  u16* Wt = blockIdx.z == 0 ? t0 : blockIdx.z == 1 ? t1 :
            blockIdx.z == 2 ? t2 : t3;
  __shared__ float t[32][33];
  int tx = threadIdx.x & 31, ty = (threadIdx.x >> 5) & 7;
#pragma unroll
  for (int j = 0; j < 32; j += 8)
    t[ty + j][tx] = W[(size_t)(blockIdx.y * 32 + ty + j) * DM + blockIdx.x * 32 + tx];
  __syncthreads();
#pragma unroll
  for (int j = 0; j < 32; j += 8)
    Wt[(size_t)(blockIdx.x * 32 + ty + j) * DM + blockIdx.y * 32 + tx] = f2bf(t[tx][ty + j]);
}

// ---------------- GEMM core: C[M,N] = (A * Bt^T + bias) * oscale -----------
// EPI 0: bf16 row-major; EPI 1: bf16 scatter Vt[(b*DM+col)*S_+s]; EPI 2: f32.
template <int EPI>
__device__ __forceinline__ void gemm_body(const u16* __restrict__ A,
                                          const u16* __restrict__ Bt,
                                          const float* __restrict__ bias,
                                          void* __restrict__ Cout,
                                          int M, int N, int K, float oscale,
                                          int bx, int by) {
  __shared__ u16 lA[128 * 32];
  __shared__ u16 lB[128 * 32];
  const int tid = threadIdx.x, wid = tid >> 6, lane = tid & 63;
  const int lr = lane & 15, lh = lane >> 4;
  const int m0 = by * 128, n0 = bx * 128;
  const int wr = wid >> 1, wc = wid & 1;

  f32x4 acc[4][4];
#pragma unroll
  for (int m = 0; m < 4; m++)
#pragma unroll
    for (int n = 0; n < 4; n++) acc[m][n] = (f32x4){0.f, 0.f, 0.f, 0.f};

  const int srow = wid * 16 + (lane >> 2);
  const int scol = (lane & 3) * 8;

  for (int k0 = 0; k0 < K; k0 += 32) {
#pragma unroll
    for (int p = 0; p < 2; p++) {
      int r = p * 64 + srow;
      gload_lds16(A + (size_t)(m0 + r) * K + k0 + scol, lA + (p * 64 + wid * 16) * 32);
      gload_lds16(Bt + (size_t)(n0 + r) * K + k0 + scol, lB + (p * 64 + wid * 16) * 32);
    }
    __syncthreads();
    short8 af[4], bf[4];
#pragma unroll
    for (int m = 0; m < 4; m++)
      af[m] = *(const short8*)(lA + (wr * 64 + m * 16 + lr) * 32 + lh * 8);
#pragma unroll
    for (int n = 0; n < 4; n++)
      bf[n] = *(const short8*)(lB + (wc * 64 + n * 16 + lr) * 32 + lh * 8);
#pragma unroll
    for (int m = 0; m < 4; m++)
#pragma unroll
      for (int n = 0; n < 4; n++) acc[m][n] = mfma16(af[m], bf[n], acc[m][n]);
    __syncthreads();
  }

#pragma unroll
  for (int m = 0; m < 4; m++) {
    int grow0 = m0 + wr * 64 + m * 16 + lh * 4;
#pragma unroll
    for (int n = 0; n < 4; n++) {
      int gcol = n0 + wc * 64 + n * 16 + lr;
      float bi = bias[gcol];
      float v0 = (acc[m][n][0] + bi) * oscale;
      float v1 = (acc[m][n][1] + bi) * oscale;
      float v2 = (acc[m][n][2] + bi) * oscale;
      float v3 = (acc[m][n][3] + bi) * oscale;
      if constexpr (EPI == 2) {
        float* C = (float*)Cout;
        C[(size_t)(grow0 + 0) * N + gcol] = v0;
        C[(size_t)(grow0 + 1) * N + gcol] = v1;
        C[(size_t)(grow0 + 2) * N + gcol] = v2;
        C[(size_t)(grow0 + 3) * N + gcol] = v3;
      } else {
        u32 p01 = cvtpk(v0, v1), p23 = cvtpk(v2, v3);
        u16* C = (u16*)Cout;
#pragma unroll
        for (int r = 0; r < 4; r++) {
          u32 pk = r < 2 ? p01 : p23;
          u16 bv = (r & 1) ? (u16)(pk >> 16) : (u16)(pk & 0xffff);
          int grow = grow0 + r;
          if constexpr (EPI == 0) {
            C[(size_t)grow * N + gcol] = bv;
          } else {
            int bb = grow >> 11, sl = grow & 2047;
            C[((size_t)(bb * DM) + gcol) * S_ + sl] = bv;
          }
        }
      }
    }
  }
}

// Q/K/V projections in ONE launch: grid (8, 64, 3); z selects operandi.
__global__ __launch_bounds__(256) void gemm_qkv(
    const u16* __restrict__ qb, const u16* __restrict__ kb, const u16* __restrict__ vb,
    const u16* __restrict__ WqT, const u16* __restrict__ WkT, const u16* __restrict__ WvT,
    const float* __restrict__ bq, const float* __restrict__ bk, const float* __restrict__ bv,
    u16* __restrict__ Qp, u16* __restrict__ Kp, u16* __restrict__ Vt, float qsc) {
  const int z = blockIdx.z;
  if (z == 0)
    gemm_body<0>(qb, WqT, bq, Qp, B_ * L_, DM, DM, qsc, blockIdx.x, blockIdx.y);
  else if (z == 1)
    gemm_body<0>(kb, WkT, bk, Kp, B_ * L_, DM, DM, 1.0f, blockIdx.x, blockIdx.y);
  else
    gemm_body<1>(vb, WvT, bv, Vt, B_ * L_, DM, DM, 1.0f, blockIdx.x, blockIdx.y);
}

__global__ __launch_bounds__(256) void gemm_out(const u16* __restrict__ A,
                                                const u16* __restrict__ Bt,
                                                const float* __restrict__ bias,
                                                float* __restrict__ C) {
  gemm_body<2>(A, Bt, bias, C, B_ * L_, DM, DM, 1.0f, blockIdx.x, blockIdx.y);
}

// ---------------- flash attention ----------------
// Swapped QK^T (lane holds all 16 scores of one q-row), log2-domain softmax
// (Q pre-scaled by 0.125*log2e in projection), defer-max, max3 reduce tree,
// f32x4 vector math (v_pk_add_f32), b64 P stores, setprio around MFMA.
__global__ __launch_bounds__(256) void attn(const u16* __restrict__ Q,
                                            const u16* __restrict__ Kp,
                                            const u16* __restrict__ Vt,
                                            u16* __restrict__ O) {
  __shared__ u16 lK[2][64 * 64];
  __shared__ u16 lV[2][64 * 64];
  __shared__ u16 lP[4][16 * 64];
  const int tid = threadIdx.x, wid = tid >> 6, lane = tid & 63;
  const int lr = lane & 15, lh = lane >> 4;

  int lin = blockIdx.x + gridDim.x * (blockIdx.y + gridDim.y * blockIdx.z);
  int swz = (lin & 7) * 256 + (lin >> 3);
  const int b = swz >> 9, h = (swz >> 5) & 15, q0 = (swz & 31) * 64;

  const u16* Qb = Q + ((size_t)(b * L_ + q0 + wid * 16 + lr)) * DM + h * E_;
  short8 bq0 = *(const short8*)(Qb + lh * 8);
  short8 bq1 = *(const short8*)(Qb + 32 + lh * 8);

  f32x4 o[4];
#pragma unroll
  for (int e = 0; e < 4; e++) o[e] = (f32x4){0.f, 0.f, 0.f, 0.f};
  float m_r = -3.0e38f, l_r = 0.f;

  const u16* Kb = Kp + ((size_t)(b * S_)) * DM + h * E_;
  const u16* Vb = Vt + ((size_t)(b * DM + h * E_)) * S_;
  const int g_r = lane >> 3;
  const int g_c = ((lane & 7) ^ g_r) * 8;
  const int sxr = (lr & 7) * 8;

  auto stage = [&](int buf, int kb) {
#pragma unroll
    for (int p = 0; p < 2; p++) {
      int row = p * 32 + wid * 8 + g_r;
      gload_lds16(Kb + (size_t)(kb + row) * DM + g_c, lK[buf] + (p * 32 + wid * 8) * 64);
      gload_lds16(Vb + (size_t)row * S_ + kb + g_c, lV[buf] + (p * 32 + wid * 8) * 64);
    }
  };

  stage(0, 0);
  const int NT = S_ / 64;
  for (int it = 0; it < NT; ++it) {
    const int buf = it & 1;
    __syncthreads();
    if (it + 1 < NT) stage(buf ^ 1, (it + 1) * 64);

    // swapped QK^T: lane (lr,lh) reg r -> score q=lr, k=kt*16+lh*4+r
    f32x4 s[4];
    __builtin_amdgcn_s_setprio(1);
#pragma unroll
    for (int kt = 0; kt < 4; kt++) {
      f32x4 a = (f32x4){0.f, 0.f, 0.f, 0.f};
      const u16* kp0 = lK[buf] + (kt * 16 + lr) * 64;
      a = mfma16(*(const short8*)(kp0 + ((lh * 8) ^ sxr)), bq0, a);
      a = mfma16(*(const short8*)(kp0 + ((lh * 8 + 32) ^ sxr)), bq1, a);
      s[kt] = a;
    }
    __builtin_amdgcn_s_setprio(0);

    // tile max: max3 triples (8 ops) + 2 shfl
    float a0 = fmaxf(fmaxf(s[0][0], s[0][1]), s[0][2]);
    float a1 = fmaxf(fmaxf(s[0][3], s[1][0]), s[1][1]);
    float a2 = fmaxf(fmaxf(s[1][2], s[1][3]), s[2][0]);
    float a3 = fmaxf(fmaxf(s[2][1], s[2][2]), s[2][3]);
    float a4 = fmaxf(fmaxf(s[3][0], s[3][1]), s[3][2]);
    float b0 = fmaxf(fmaxf(a0, a1), a2);
    float b1 = fmaxf(fmaxf(a3, a4), s[3][3]);
    float t = fmaxf(b0, b1);
    t = fmaxf(t, __shfl_xor(t, 16));
    t = fmaxf(t, __shfl_xor(t, 32));

    // defer-max rescale (log2 domain, THR=8)
    if (__any(t > m_r + 8.f)) {
      float mn = fmaxf(m_r, t);
      float al = exp2a(m_r - mn);
      m_r = mn;
      l_r *= al;
      float alq[4];
#pragma unroll
      for (int r = 0; r < 4; r++) alq[r] = __shfl(al, (lane & 48) | (lh * 4 + r));
#pragma unroll
      for (int e = 0; e < 4; e++)
#pragma unroll
        for (int r = 0; r < 4; r++) o[e][r] *= alq[r];
    }

    // p = exp2(s - m): vector subs (pk_add), scalar exp2, packed bf16 b64 store
    u16* Pw = lP[wid];
    f32x4 mv = (f32x4){m_r, m_r, m_r, m_r};
    f32x4 p[4];
#pragma unroll
    for (int kt = 0; kt < 4; kt++) {
      f32x4 d = s[kt] - mv;
      p[kt][0] = exp2a(d[0]); p[kt][1] = exp2a(d[1]);
      p[kt][2] = exp2a(d[2]); p[kt][3] = exp2a(d[3]);
      u32x2 pk;
      pk.x = cvtpk(p[kt][0], p[kt][1]);
      pk.y = cvtpk(p[kt][2], p[kt][3]);
      *(u32x2*)(Pw + lr * 64 + ((kt * 16 + lh * 4) ^ sxr)) = pk;
    }
    f32x4 rv = (p[0] + p[1]) + (p[2] + p[3]);
    float rs = (rv[0] + rv[1]) + (rv[2] + rv[3]);
    rs += __shfl_xor(rs, 16);
    rs += __shfl_xor(rs, 32);
    l_r += rs;

    // PV
    __builtin_amdgcn_s_setprio(1);
#pragma unroll
    for (int kc = 0; kc < 2; kc++) {
      short8 pa = *(const short8*)(Pw + lr * 64 + ((kc * 32 + lh * 8) ^ sxr));
#pragma unroll
      for (int e = 0; e < 4; e++) {
        short8 vb = *(const short8*)(lV[buf] + (e * 16 + lr) * 64 + ((kc * 32 + lh * 8) ^ sxr));
        o[e] = mfma16(pa, vb, o[e]);
      }
    }
    __builtin_amdgcn_s_setprio(0);
  }

  float lq[4];
#pragma unroll
  for (int r = 0; r < 4; r++)
    lq[r] = 1.f / __shfl(l_r, (lane & 48) | (lh * 4 + r));

  u16* Ob = O + ((size_t)(b * L_ + q0 + wid * 16 + lh * 4)) * DM + h * E_;
#pragma unroll
  for (int e = 0; e < 4; e++) {
    u32 q01 = cvtpk(o[e][0] * lq[0], o[e][1] * lq[1]);
    u32 q23 = cvtpk(o[e][2] * lq[2], o[e][3] * lq[3]);
    Ob[(size_t)0 * DM + e * 16 + lr] = (u16)(q01 & 0xffff);
    Ob[(size_t)1 * DM + e * 16 + lr] = (u16)(q01 >> 16);
    Ob[(size_t)2 * DM + e * 16 + lr] = (u16)(q23 & 0xffff);
    Ob[(size_t)3 * DM + e * 16 + lr] = (u16)(q23 >> 16);
  }
}

extern "C" void kernel_launch(void* const* d_in, const int* in_sizes, int n_in,
                              void* d_out, int out_size, void* d_ws, size_t ws_size,
                              hipStream_t stream) {
  (void)in_sizes; (void)n_in; (void)out_size; (void)ws_size;
  const float* q  = (const float*)d_in[0];
  const float* k  = (const float*)d_in[1];
  const float* v  = (const float*)d_in[2];
  const float* Wq = (const float*)d_in[3];
  const float* bq = (const float*)d_in[4];
  const float* Wk = (const float*)d_in[5];
  const float* bk = (const float*)d_in[6];
  const float* Wv = (const float*)d_in[7];
  const float* bv = (const float*)d_in[8];
  const float* Wo = (const float*)d_in[9];
  const float* bo = (const float*)d_in[10];

  char* w = (char*)d_ws;
  const size_t ACT = (size_t)B_ * L_ * DM * 2;  // 16 MiB
  const size_t WT  = (size_t)DM * DM * 2;       // 2 MiB
  u16* qb  = (u16*)w; w += ACT;
  u16* kb  = (u16*)w; w += ACT;
  u16* vb  = (u16*)w; w += ACT;
  u16* WqT = (u16*)w; w += WT;
  u16* WkT = (u16*)w; w += WT;
  u16* WvT = (u16*)w; w += WT;
  u16* WoT = (u16*)w; w += WT;
  u16* Qp  = (u16*)w; w += ACT;
  u16* Kp  = (u16*)w; w += ACT;
  u16* Vt  = (u16*)w; w += ACT;
  u16* At  = (u16*)w; w += ACT;

  const int M = B_ * L_;  // 8192
  cvt_all<<<dim3(M * DM / (4 * 256), 3), 256, 0, stream>>>(q, k, v, qb, kb, vb);
  transp_all<<<dim3(32, 32, 4), 256, 0, stream>>>(Wq, Wk, Wv, Wo, WqT, WkT, WvT, WoT);

  const float QSC = 0.125f * 1.44269504089f;  // 1/sqrt(64) * log2(e)
  gemm_qkv<<<dim3(DM / 128, M / 128, 3), 256, 0, stream>>>(
      qb, kb, vb, WqT, WkT, WvT, bq, bk, bv, Qp, Kp, Vt, QSC);

  attn<<<dim3(L_ / 64, H_, B_), 256, 0, stream>>>(Qp, Kp, Vt, At);

  gemm_out<<<dim3(DM / 128, M / 128), 256, 0, stream>>>(At, WoT, bo, (float*)d_out);
}

// Round 5
// 242.185 us; speedup vs baseline: 1.8534x; 1.0899x over previous
//
#include <hip/hip_runtime.h>
#include <hip/hip_bf16.h>

typedef unsigned short u16;
typedef unsigned int u32;
using short8 = __attribute__((ext_vector_type(8))) short;
using f32x4  = __attribute__((ext_vector_type(4))) float;
using f32x16 = __attribute__((ext_vector_type(16))) float;
using u32x2  = __attribute__((ext_vector_type(2))) unsigned int;
using u32x4  = __attribute__((ext_vector_type(4))) unsigned int;

#define B_  4
#define L_  2048
#define S_  2048
#define DM  1024
#define H_  16
#define E_  64

__device__ __forceinline__ u16 f2bf(float f) {
  union { float f; unsigned u; } v; v.f = f;
  unsigned u = v.u;
  unsigned r = (u + 0x7fffu + ((u >> 16) & 1u)) >> 16;  // RNE
  return (u16)r;
}

__device__ __forceinline__ float exp2a(float x) {
  float r; asm("v_exp_f32 %0, %1" : "=v"(r) : "v"(x)); return r;
}

__device__ __forceinline__ u32 cvtpk(float lo, float hi) {
  u32 r; asm("v_cvt_pk_bf16_f32 %0, %1, %2" : "=v"(r) : "v"(lo), "v"(hi));
  return r;
}

__device__ __forceinline__ f32x4 mfma16(short8 a, short8 b, f32x4 c) {
  return __builtin_amdgcn_mfma_f32_16x16x32_bf16(a, b, c, 0, 0, 0);
}

__device__ __forceinline__ f32x16 mfma32(short8 a, short8 b, f32x16 c) {
  return __builtin_amdgcn_mfma_f32_32x32x16_bf16(a, b, c, 0, 0, 0);
}

__device__ __forceinline__ void gload_lds16(const u16* g, u16* l) {
  __builtin_amdgcn_global_load_lds(
      (const __attribute__((address_space(1))) unsigned int*)(const void*)g,
      (__attribute__((address_space(3))) unsigned int*)(void*)l, 16, 0, 0);
}

// ---------------- fused fp32 -> bf16 convert for q,k,v (one launch) --------
__global__ __launch_bounds__(256) void cvt_all(const float* __restrict__ s0,
                                               const float* __restrict__ s1,
                                               const float* __restrict__ s2,
                                               u16* __restrict__ d0,
                                               u16* __restrict__ d1,
                                               u16* __restrict__ d2) {
  const float* s = blockIdx.y == 0 ? s0 : blockIdx.y == 1 ? s1 : s2;
  u16* d = blockIdx.y == 0 ? d0 : blockIdx.y == 1 ? d1 : d2;
  int i = (blockIdx.x * 256 + threadIdx.x) * 4;
  f32x4 v = *(const f32x4*)(s + i);
  u32x2 o;
  o.x = cvtpk(v.x, v.y);
  o.y = cvtpk(v.z, v.w);
  *(u32x2*)(d + i) = o;
}

// ---------------- fused weight transpose+convert (one launch, z=4) ---------
__global__ __launch_bounds__(256) void transp_all(const float* __restrict__ w0,
                                                  const float* __restrict__ w1,
                                                  const float* __restrict__ w2,
                                                  const float* __restrict__ w3,
                                                  u16* __restrict__ t0,
                                                  u16* __restrict__ t1,
                                                  u16* __restrict__ t2,
                                                  u16* __restrict__ t3) {
  const float* W = blockIdx.z == 0 ? w0 : blockIdx.z == 1 ? w1 :
                   blockIdx.z == 2 ? w2 : w3;
  u16* Wt = blockIdx.z == 0 ? t0 : blockIdx.z == 1 ? t1 :
            blockIdx.z == 2 ? t2 : t3;
  __shared__ float t[32][33];
  int tx = threadIdx.x & 31, ty = (threadIdx.x >> 5) & 7;
#pragma unroll
  for (int j = 0; j < 32; j += 8)
    t[ty + j][tx] = W[(size_t)(blockIdx.y * 32 + ty + j) * DM + blockIdx.x * 32 + tx];
  __syncthreads();
#pragma unroll
  for (int j = 0; j < 32; j += 8)
    Wt[(size_t)(blockIdx.x * 32 + ty + j) * DM + blockIdx.y * 32 + tx] = f2bf(t[tx][ty + j]);
}

// ---------------- GEMM core: C[M,N] = (A * Bt^T + bias) * oscale -----------
// EPI 0: bf16 row-major; EPI 1: bf16 scatter Vt[(b*DM+col)*S_+s]; EPI 2: f32.
template <int EPI>
__device__ __forceinline__ void gemm_body(const u16* __restrict__ A,
                                          const u16* __restrict__ Bt,
                                          const float* __restrict__ bias,
                                          void* __restrict__ Cout,
                                          int M, int N, int K, float oscale,
                                          int bx, int by) {
  __shared__ u16 lA[128 * 32];
  __shared__ u16 lB[128 * 32];
  const int tid = threadIdx.x, wid = tid >> 6, lane = tid & 63;
  const int lr = lane & 15, lh = lane >> 4;
  const int m0 = by * 128, n0 = bx * 128;
  const int wr = wid >> 1, wc = wid & 1;

  f32x4 acc[4][4];
#pragma unroll
  for (int m = 0; m < 4; m++)
#pragma unroll
    for (int n = 0; n < 4; n++) acc[m][n] = (f32x4){0.f, 0.f, 0.f, 0.f};

  const int srow = wid * 16 + (lane >> 2);
  const int scol = (lane & 3) * 8;

  for (int k0 = 0; k0 < K; k0 += 32) {
#pragma unroll
    for (int p = 0; p < 2; p++) {
      int r = p * 64 + srow;
      gload_lds16(A + (size_t)(m0 + r) * K + k0 + scol, lA + (p * 64 + wid * 16) * 32);
      gload_lds16(Bt + (size_t)(n0 + r) * K + k0 + scol, lB + (p * 64 + wid * 16) * 32);
    }
    __syncthreads();
    short8 af[4], bf[4];
#pragma unroll
    for (int m = 0; m < 4; m++)
      af[m] = *(const short8*)(lA + (wr * 64 + m * 16 + lr) * 32 + lh * 8);
#pragma unroll
    for (int n = 0; n < 4; n++)
      bf[n] = *(const short8*)(lB + (wc * 64 + n * 16 + lr) * 32 + lh * 8);
#pragma unroll
    for (int m = 0; m < 4; m++)
#pragma unroll
      for (int n = 0; n < 4; n++) acc[m][n] = mfma16(af[m], bf[n], acc[m][n]);
    __syncthreads();
  }

#pragma unroll
  for (int m = 0; m < 4; m++) {
    int grow0 = m0 + wr * 64 + m * 16 + lh * 4;
#pragma unroll
    for (int n = 0; n < 4; n++) {
      int gcol = n0 + wc * 64 + n * 16 + lr;
      float bi = bias[gcol];
      float v0 = (acc[m][n][0] + bi) * oscale;
      float v1 = (acc[m][n][1] + bi) * oscale;
      float v2 = (acc[m][n][2] + bi) * oscale;
      float v3 = (acc[m][n][3] + bi) * oscale;
      if constexpr (EPI == 2) {
        float* C = (float*)Cout;
        C[(size_t)(grow0 + 0) * N + gcol] = v0;
        C[(size_t)(grow0 + 1) * N + gcol] = v1;
        C[(size_t)(grow0 + 2) * N + gcol] = v2;
        C[(size_t)(grow0 + 3) * N + gcol] = v3;
      } else {
        u32 p01 = cvtpk(v0, v1), p23 = cvtpk(v2, v3);
        u16* C = (u16*)Cout;
#pragma unroll
        for (int r = 0; r < 4; r++) {
          u32 pk = r < 2 ? p01 : p23;
          u16 bv = (r & 1) ? (u16)(pk >> 16) : (u16)(pk & 0xffff);
          int grow = grow0 + r;
          if constexpr (EPI == 0) {
            C[(size_t)grow * N + gcol] = bv;
          } else {
            int bb = grow >> 11, sl = grow & 2047;
            C[((size_t)(bb * DM) + gcol) * S_ + sl] = bv;
          }
        }
      }
    }
  }
}

// Q/K/V projections in ONE launch: grid (8, 64, 3); z selects operandi.
__global__ __launch_bounds__(256) void gemm_qkv(
    const u16* __restrict__ qb, const u16* __restrict__ kb, const u16* __restrict__ vb,
    const u16* __restrict__ WqT, const u16* __restrict__ WkT, const u16* __restrict__ WvT,
    const float* __restrict__ bq, const float* __restrict__ bk, const float* __restrict__ bv,
    u16* __restrict__ Qp, u16* __restrict__ Kp, u16* __restrict__ Vt, float qsc) {
  const int z = blockIdx.z;
  if (z == 0)
    gemm_body<0>(qb, WqT, bq, Qp, B_ * L_, DM, DM, qsc, blockIdx.x, blockIdx.y);
  else if (z == 1)
    gemm_body<0>(kb, WkT, bk, Kp, B_ * L_, DM, DM, 1.0f, blockIdx.x, blockIdx.y);
  else
    gemm_body<1>(vb, WvT, bv, Vt, B_ * L_, DM, DM, 1.0f, blockIdx.x, blockIdx.y);
}

__global__ __launch_bounds__(256) void gemm_out(const u16* __restrict__ A,
                                                const u16* __restrict__ Bt,
                                                const float* __restrict__ bias,
                                                float* __restrict__ C) {
  gemm_body<2>(A, Bt, bias, C, B_ * L_, DM, DM, 1.0f, blockIdx.x, blockIdx.y);
}

// ---------------- flash attention, 32x32x16 MFMA ----------------
// 4 waves x 32 q-rows = 128 q/block. Swapped QK^T (A=K, B=Q) on 32x32x16:
// scores D[k][q]: lane owns q=lane&31; reg r -> k = 32kt + (r&3)+8*(r>>2)+4*hi.
// PV computed as out[e][q] (A=V, B=P) with the contraction index RELABELED so
// the lane's cvt_pk-packed exp words directly form the PV B-fragment:
// B row hi*8+j <-> k = 32kt+16su+4hi+8*(j>>2)+(j&3) == own regs 8su..8su+7.
// V fragment = 2x ds_read_b64 per mfma through the same permutation.
// m,l,o all lane-local (only shfl_xor(32) reductions). K/V LDS XOR-swizzled,
// staged by global_load_lds with pre-swizzled source; double-buffered.
__global__ __launch_bounds__(256, 3) void attn(const u16* __restrict__ Q,
                                               const u16* __restrict__ Kp,
                                               const u16* __restrict__ Vt,
                                               u16* __restrict__ O) {
  __shared__ u16 lK[2][64 * 64];
  __shared__ u16 lV[2][64 * 64];
  const int tid = threadIdx.x, wid = tid >> 6, lane = tid & 63;
  const int l31 = lane & 31, hi = lane >> 5;

  // XCD-aware remap: 1024 blocks, 128 consecutive per XCD
  int lin = blockIdx.x + gridDim.x * (blockIdx.y + gridDim.y * blockIdx.z);
  int swz = (lin & 7) * 128 + (lin >> 3);
  const int b = swz >> 8, h = (swz >> 4) & 15, q0 = (swz & 15) * 128;
  const int qrow = q0 + wid * 32 + l31;

  // Q fragments (B-operand): step s covers d = s*16 + hi*8 .. +8
  const u16* Qb = Q + ((size_t)(b * L_ + qrow)) * DM + h * E_ + hi * 8;
  short8 qf[4];
#pragma unroll
  for (int s = 0; s < 4; s++) qf[s] = *(const short8*)(Qb + s * 16);

  f32x16 o[2];
#pragma unroll
  for (int et = 0; et < 2; et++)
#pragma unroll
    for (int r = 0; r < 16; r++) o[et][r] = 0.f;
  float m_r = -3.0e38f, l_r = 0.f;

  const u16* Kb = Kp + ((size_t)(b * S_)) * DM + h * E_;
  const u16* Vb = Vt + ((size_t)(b * DM + h * E_)) * S_;
  const int g_r = lane >> 3;
  const int g_c = ((lane & 7) ^ g_r) * 8;    // pre-swizzled source chunk
  const int sxk = (l31 & 7) * 8;             // read-side XOR (u16 units)
  const int hi4 = hi * 4, hi8 = hi * 8;

  auto stage = [&](int buf, int kb) {
#pragma unroll
    for (int p = 0; p < 2; p++) {
      int row = p * 32 + wid * 8 + g_r;
      gload_lds16(Kb + (size_t)(kb + row) * DM + g_c, lK[buf] + (p * 32 + wid * 8) * 64);
      gload_lds16(Vb + (size_t)row * S_ + kb + g_c, lV[buf] + (p * 32 + wid * 8) * 64);
    }
  };

  stage(0, 0);
  const int NT = S_ / 64;
  for (int it = 0; it < NT; ++it) {
    const int buf = it & 1;
    __syncthreads();
    if (it + 1 < NT) stage(buf ^ 1, (it + 1) * 64);

    // QK^T: 2 k-tiles of 32, 4 K-steps of 16 d each
    f32x16 sc[2];
    __builtin_amdgcn_s_setprio(1);
#pragma unroll
    for (int kt = 0; kt < 2; kt++) {
      f32x16 a;
#pragma unroll
      for (int r = 0; r < 16; r++) a[r] = 0.f;
      const u16* kp = lK[buf] + (kt * 32 + l31) * 64;
#pragma unroll
      for (int s = 0; s < 4; s++) {
        short8 kf = *(const short8*)(kp + ((s * 16 + hi8) ^ sxk));
        a = mfma32(kf, qf[s], a);
      }
      sc[kt] = a;
    }
    __builtin_amdgcn_s_setprio(0);

    // per-q tile max: 31 in-lane fmax (max3-fusable) + 1 cross-half
    float tm = sc[0][0];
#pragma unroll
    for (int r = 1; r < 16; r++) tm = fmaxf(tm, sc[0][r]);
#pragma unroll
    for (int r = 0; r < 16; r++) tm = fmaxf(tm, sc[1][r]);
    tm = fmaxf(tm, __shfl_xor(tm, 32));

    // defer-max rescale (log2 domain, THR=8)
    if (__any(tm > m_r + 8.f)) {
      float mn = fmaxf(m_r, tm);
      float al = exp2a(m_r - mn);
      m_r = mn;
      l_r *= al;
#pragma unroll
      for (int et = 0; et < 2; et++)
#pragma unroll
        for (int r = 0; r < 16; r++) o[et][r] *= al;
    }

    // p = exp2(s - m); pack pairs -> PV B-frag words (in-register, no LDS)
    u32 wp[2][8];
    float rs = 0.f;
#pragma unroll
    for (int kt = 0; kt < 2; kt++)
#pragma unroll
      for (int i = 0; i < 8; i++) {
        float p0 = exp2a(sc[kt][2 * i] - m_r);
        float p1 = exp2a(sc[kt][2 * i + 1] - m_r);
        rs += p0 + p1;
        wp[kt][i] = cvtpk(p0, p1);
      }
    rs += __shfl_xor(rs, 32);
    l_r += rs;

    // PV: out[e][q] += V^T * P, contraction relabeled to match reg layout
    __builtin_amdgcn_s_setprio(1);
#pragma unroll
    for (int et = 0; et < 2; et++) {
      const u16* vp = lV[buf] + (et * 32 + l31) * 64;
#pragma unroll
      for (int kt = 0; kt < 2; kt++)
#pragma unroll
        for (int su = 0; su < 2; su++) {
          int koff = kt * 32 + su * 16 + hi4;
          u32x2 lo = *(const u32x2*)(vp + (koff ^ sxk));
          u32x2 hp = *(const u32x2*)(vp + ((koff + 8) ^ sxk));
          u32x4 vv = {lo.x, lo.y, hp.x, hp.y};
          u32x4 pv = {wp[kt][su * 4 + 0], wp[kt][su * 4 + 1],
                      wp[kt][su * 4 + 2], wp[kt][su * 4 + 3]};
          o[et] = mfma32(*(const short8*)&vv, *(const short8*)&pv, o[et]);
        }
    }
    __builtin_amdgcn_s_setprio(0);
  }

  // epilogue: lane-local normalize; o reg r -> e = (r&3)+8*(r>>2)+4*hi+32*et
  float inv = 1.f / l_r;
  u16* Ob = O + ((size_t)(b * L_ + qrow)) * DM + h * E_;
#pragma unroll
  for (int et = 0; et < 2; et++)
#pragma unroll
    for (int t = 0; t < 4; t++) {
      u32x2 pk;
      pk.x = cvtpk(o[et][4 * t] * inv, o[et][4 * t + 1] * inv);
      pk.y = cvtpk(o[et][4 * t + 2] * inv, o[et][4 * t + 3] * inv);
      *(u32x2*)(Ob + et * 32 + t * 8 + hi4) = pk;
    }
}

extern "C" void kernel_launch(void* const* d_in, const int* in_sizes, int n_in,
                              void* d_out, int out_size, void* d_ws, size_t ws_size,
                              hipStream_t stream) {
  (void)in_sizes; (void)n_in; (void)out_size; (void)ws_size;
  const float* q  = (const float*)d_in[0];
  const float* k  = (const float*)d_in[1];
  const float* v  = (const float*)d_in[2];
  const float* Wq = (const float*)d_in[3];
  const float* bq = (const float*)d_in[4];
  const float* Wk = (const float*)d_in[5];
  const float* bk = (const float*)d_in[6];
  const float* Wv = (const float*)d_in[7];
  const float* bv = (const float*)d_in[8];
  const float* Wo = (const float*)d_in[9];
  const float* bo = (const float*)d_in[10];

  char* w = (char*)d_ws;
  const size_t ACT = (size_t)B_ * L_ * DM * 2;  // 16 MiB
  const size_t WT  = (size_t)DM * DM * 2;       // 2 MiB
  u16* qb  = (u16*)w; w += ACT;
  u16* kb  = (u16*)w; w += ACT;
  u16* vb  = (u16*)w; w += ACT;
  u16* WqT = (u16*)w; w += WT;
  u16* WkT = (u16*)w; w += WT;
  u16* WvT = (u16*)w; w += WT;
  u16* WoT = (u16*)w; w += WT;
  u16* Qp  = (u16*)w; w += ACT;
  u16* Kp  = (u16*)w; w += ACT;
  u16* Vt  = (u16*)w; w += ACT;
  u16* At  = (u16*)w; w += ACT;

  const int M = B_ * L_;  // 8192
  cvt_all<<<dim3(M * DM / (4 * 256), 3), 256, 0, stream>>>(q, k, v, qb, kb, vb);
  transp_all<<<dim3(32, 32, 4), 256, 0, stream>>>(Wq, Wk, Wv, Wo, WqT, WkT, WvT, WoT);

  const float QSC = 0.125f * 1.44269504089f;  // 1/sqrt(64) * log2(e)
  gemm_qkv<<<dim3(DM / 128, M / 128, 3), 256, 0, stream>>>(
      qb, kb, vb, WqT, WkT, WvT, bq, bk, bv, Qp, Kp, Vt, QSC);

  attn<<<dim3(L_ / 128, H_, B_), 256, 0, stream>>>(Qp, Kp, Vt, At);

  gemm_out<<<dim3(DM / 128, M / 128), 256, 0, stream>>>(At, WoT, bo, (float*)d_out);
}